// Round 2
// baseline (1004.553 us; speedup 1.0000x reference)
//
#include <hip/hip_runtime.h>
#include <hip/hip_bf16.h>
#include <math.h>

typedef __hip_bfloat16 bf16;
#define DEVINL __device__ __forceinline__

constexpr int Bc  = 2;
constexpr int Nc  = 768;
constexpr int Dc  = 512;
constexpr int Hc  = 8;
constexpr int DKc = 64;
constexpr int BHc = Bc * Hc;
constexpr float SCALE    = 0.125f;   // 1/sqrt(64)
constexpr float EPSF     = 1e-6f;
constexpr float BETA_NOT = 0.5f;

DEVINL float ldf(const float* p, long i) { return p[i]; }
DEVINL float ldf(const bf16* p, long i) { return __bfloat162float(p[i]); }
DEVINL void stf(float* p, long i, float v) { p[i] = v; }
DEVINL void stf(bf16* p, long i, float v) { p[i] = __float2bfloat16(v); }

// ---------------------------------------------------------------------------
// Dtype sniffer: decode first 128 u16 of x as bf16. If the buffer really holds
// fp32 data, even-index elements are fp32-mantissa bits -> random exponents ->
// max blows past 1000 with overwhelming probability. Deterministic per launch.
// ---------------------------------------------------------------------------
DEVINL int sniff_is_fp32(const void* xraw) {
    const unsigned short* p = (const unsigned short*)xraw;
    float mx = 0.f;
#pragma unroll 1
    for (int j = 0; j < 128; ++j) {
        float v = __uint_as_float(((unsigned)p[j]) << 16);
        mx = fmaxf(mx, fabsf(v));   // fmaxf drops NaN
    }
    return mx > 1000.f ? 1 : 0;
}

DEVINL float cvt_elem(const void* s, long j, int is32) {
    return is32 ? ((const float*)s)[j]
                : __bfloat162float(((const bf16*)s)[j]);
}

// Convert all inputs to fp32 scratch. Grid-stride over the largest (786432).
__global__ __launch_bounds__(256) void convert_inputs(
    const void* x, const void* w1, const void* w2, const void* pw,
    const void* c1w, const void* c1b, const void* c2w, const void* c2b,
    const void* ch,
    float* xf, float* w1f, float* w2f, float* pwf, float* smallf)
{
    const int is32 = sniff_is_fp32(x);
    const long i = (long)blockIdx.x * 256 + threadIdx.x;
    if (i < (long)Bc * Nc * Dc) {           // 786432
        xf[i]  = cvt_elem(x,  i, is32);
        w1f[i] = cvt_elem(w1, i, is32);
        w2f[i] = cvt_elem(w2, i, is32);
    }
    if (i < (long)Dc * Dc) pwf[i] = cvt_elem(pw, i, is32);   // 262144
    if (i < 96)       smallf[i] = cvt_elem(c1w, i,        is32);
    else if (i < 112) smallf[i] = cvt_elem(c1b, i - 96,   is32);
    else if (i < 176) smallf[i] = cvt_elem(c2w, i - 112,  is32);
    else if (i < 180) smallf[i] = cvt_elem(c2b, i - 176,  is32);
    else if (i == 180) smallf[180] = cvt_elem(ch, 0, is32);
}

// Sentinel: ws too small -> absmax ~= 7 under both bf16 and fp32 readback.
__global__ __launch_bounds__(256) void fill_sentinel(unsigned short* o) {
    const long i = (long)blockIdx.x * 256 + threadIdx.x;
    if (i < (long)Bc * Nc * Dc) o[i] = 0x40E0;  // bf16 7.0
}

// ---------------------------------------------------------------------------
// Generic 64x64-tile GEMM, 256 threads, 4x4 micro-tile, fp32 accumulate.
// C[r,c] = alpha * sum_k A[r,k]*B[k,c]   (TRANS_B: B src is (Nm,K) row-major)
// EPI: 0 = plain store, 1 = log(max(x,0) + EPS)
// Requires M%64==0, Nm%64==0, K%16==0.
// ---------------------------------------------------------------------------
template <typename TA, typename TB, typename TC, bool TRANS_B, int EPI>
__global__ __launch_bounds__(256) void gemm_tile(
    const TA* __restrict__ Ag, const TB* __restrict__ Bg, TC* __restrict__ Cg,
    int M, int Nm, int K, int lda, int ldb, int ldc,
    long sA, long sB, long sC, float alpha)
{
    __shared__ float As[16][68];  // [k][row]; 272B rows -> float4-aligned
    __shared__ float Bs[16][68];  // [k][col]

    const int bz = blockIdx.z;
    const TA* A = Ag + (long)bz * sA;
    const TB* B = Bg + (long)bz * sB;
    TC*       C = Cg + (long)bz * sC;

    const int r0 = blockIdx.y * 64;
    const int c0 = blockIdx.x * 64;
    const int tid = threadIdx.x;
    const int tx = tid & 15, ty = tid >> 4;

    float acc[4][4] = {};

    for (int k0 = 0; k0 < K; k0 += 16) {
        {   // A tile: 64 rows x 16 k, coalesced along k
            int kk = tid & 15;
            int rbase = tid >> 4;
#pragma unroll
            for (int i = 0; i < 4; ++i) {
                int row = rbase + i * 16;
                As[kk][row] = ldf(A, (long)(r0 + row) * lda + k0 + kk);
            }
        }
        if (!TRANS_B) {  // B tile: 16 k x 64 cols, coalesced along cols
            int cc = tid & 63;
            int kb = tid >> 6;
#pragma unroll
            for (int i = 0; i < 4; ++i) {
                int kk = kb + i * 4;
                Bs[kk][cc] = ldf(B, (long)(k0 + kk) * ldb + c0 + cc);
            }
        } else {         // B src (Nm,K): coalesced along k
            int kk = tid & 15;
            int cb = tid >> 4;
#pragma unroll
            for (int i = 0; i < 4; ++i) {
                int cc = cb + i * 16;
                Bs[kk][cc] = ldf(B, (long)(c0 + cc) * ldb + k0 + kk);
            }
        }
        __syncthreads();
#pragma unroll
        for (int kk = 0; kk < 16; ++kk) {
            float4 a4 = *(const float4*)&As[kk][ty * 4];
            float4 b4 = *(const float4*)&Bs[kk][tx * 4];
            float av[4] = {a4.x, a4.y, a4.z, a4.w};
            float bv[4] = {b4.x, b4.y, b4.z, b4.w};
#pragma unroll
            for (int i = 0; i < 4; ++i)
#pragma unroll
                for (int j = 0; j < 4; ++j)
                    acc[i][j] = fmaf(av[i], bv[j], acc[i][j]);
        }
        __syncthreads();
    }

#pragma unroll
    for (int i = 0; i < 4; ++i) {
        int row = r0 + ty * 4 + i;
#pragma unroll
        for (int j = 0; j < 4; ++j) {
            int col = c0 + tx * 4 + j;
            float v = acc[i][j] * alpha;
            if (EPI == 1) v = __logf(fmaxf(v, 0.f) + EPSF);
            stf(C, (long)row * ldc + col, v);
        }
    }
}

// ---------------------------------------------------------------------------
// QKV projection: X (B*N, D) @ W (D, 3D) fp32, scatter to q/k/v (B,H,N,DK).
// ---------------------------------------------------------------------------
__global__ __launch_bounds__(256) void gemm_qkv(
    const float* __restrict__ X, const float* __restrict__ W,
    float* __restrict__ Q, float* __restrict__ Ko, float* __restrict__ V)
{
    __shared__ float As[16][68];
    __shared__ float Bs[16][68];
    const int r0 = blockIdx.y * 64;
    const int c0 = blockIdx.x * 64;
    const int tid = threadIdx.x;
    const int tx = tid & 15, ty = tid >> 4;

    float acc[4][4] = {};

    for (int k0 = 0; k0 < Dc; k0 += 16) {
        {
            int kk = tid & 15;
            int rbase = tid >> 4;
#pragma unroll
            for (int i = 0; i < 4; ++i) {
                int row = rbase + i * 16;
                As[kk][row] = X[(long)(r0 + row) * Dc + k0 + kk];
            }
        }
        {
            int cc = tid & 63;
            int kb = tid >> 6;
#pragma unroll
            for (int i = 0; i < 4; ++i) {
                int kk = kb + i * 4;
                Bs[kk][cc] = W[(long)(k0 + kk) * (3 * Dc) + c0 + cc];
            }
        }
        __syncthreads();
#pragma unroll
        for (int kk = 0; kk < 16; ++kk) {
            float4 a4 = *(const float4*)&As[kk][ty * 4];
            float4 b4 = *(const float4*)&Bs[kk][tx * 4];
            float av[4] = {a4.x, a4.y, a4.z, a4.w};
            float bv[4] = {b4.x, b4.y, b4.z, b4.w};
#pragma unroll
            for (int i = 0; i < 4; ++i)
#pragma unroll
                for (int j = 0; j < 4; ++j)
                    acc[i][j] = fmaf(av[i], bv[j], acc[i][j]);
        }
        __syncthreads();
    }

#pragma unroll
    for (int i = 0; i < 4; ++i) {
        int row = r0 + ty * 4 + i;
        int b = row >= Nc ? 1 : 0;
        int n = row - b * Nc;
        int cbase = c0 + tx * 4;       // 4-col group never crosses a 64-boundary
        int t = cbase >> 9;
        int h = (cbase & 511) >> 6;
        float* dst = (t == 0) ? Q : (t == 1) ? Ko : V;
        long base = (((long)b * Hc + h) * Nc + n) * DKc;
#pragma unroll
        for (int j = 0; j < 4; ++j) {
            int dk = (cbase + j) & 63;
            dst[base + dk] = acc[i][j];
        }
    }
}

// ---------------------------------------------------------------------------
// Row softmax over width 768 (one 256-thread block per row). Dst templated.
// No __restrict__: used in-place for Smix.
// ---------------------------------------------------------------------------
template <typename TO>
__global__ __launch_bounds__(256) void softmax_rows(const float* src, TO* dst)
{
    __shared__ float red[4];
    const long row = blockIdx.x;
    const float* s = src + row * Nc;
    TO* d = dst + row * Nc;
    const int tid = threadIdx.x;

    float v[3];
    float m = -1e30f;
#pragma unroll
    for (int i = 0; i < 3; ++i) { v[i] = s[tid + i * 256]; m = fmaxf(m, v[i]); }

#pragma unroll
    for (int off = 32; off > 0; off >>= 1) m = fmaxf(m, __shfl_down(m, off, 64));
    if ((tid & 63) == 0) red[tid >> 6] = m;
    __syncthreads();
    if (tid == 0) {
        float mm = red[0];
        for (int w = 1; w < 4; ++w) mm = fmaxf(mm, red[w]);
        red[0] = mm;
    }
    __syncthreads();
    m = red[0];
    __syncthreads();

    float e[3];
    float sum = 0.f;
#pragma unroll
    for (int i = 0; i < 3; ++i) { e[i] = __expf(v[i] - m); sum += e[i]; }
#pragma unroll
    for (int off = 32; off > 0; off >>= 1) sum += __shfl_down(sum, off, 64);
    if ((tid & 63) == 0) red[tid >> 6] = sum;
    __syncthreads();
    if (tid == 0) red[0] = red[0] + red[1] + red[2] + red[3];
    __syncthreads();
    const float inv = 1.f / fmaxf(red[0], 1e-30f);
#pragma unroll
    for (int i = 0; i < 3; ++i) stf(d, tid + i * 256, e[i] * inv);
}

// ---------------------------------------------------------------------------
// Gate network + Smix -> separate fp32 buffer. Cr/Cl read as bf16 features.
// ---------------------------------------------------------------------------
__global__ __launch_bounds__(256) void gates_smix(
    const float* __restrict__ S1g, const float* __restrict__ S2g,
    const bf16* __restrict__ Crg, const bf16* __restrict__ Clg,
    float* __restrict__ Smixg, const float* __restrict__ smallf)
{
    __shared__ float t1t[16][17], t2t[16][17];
    __shared__ float cs[192];

    const int bh = blockIdx.z;
    const long mat = (long)bh * Nc * Nc;
    const float* S1 = S1g + mat;
    const float* S2 = S2g + mat;
    const bf16*  Cr = Crg + mat;
    const bf16*  Cl = Clg + mat;
    float* Smix = Smixg + mat;

    const int tid = threadIdx.x;
    if (tid < 192) cs[tid] = smallf[tid];   // w1[96] b1[16] w2[64] b2[4] chain

    const int n0 = blockIdx.y * 16, m0 = blockIdx.x * 16;
    const int tx = tid & 15, ty = tid >> 4;

    t1t[ty][tx] = S1[(long)(m0 + ty) * Nc + n0 + tx];
    t2t[ty][tx] = S2[(long)(m0 + ty) * Nc + n0 + tx];
    __syncthreads();

    const float* cw1 = cs;       const float* cb1 = cs + 96;
    const float* cw2 = cs + 112; const float* cb2 = cs + 176;

    const int n = n0 + ty, mcol = m0 + tx;
    const long idx = (long)n * Nc + mcol;
    const float s1 = S1[idx], s2 = S2[idx];
    const float s1t = t1t[tx][ty], s2t = t2t[tx][ty];
    const float cr = __bfloat162float(Cr[idx]), cl = __bfloat162float(Cl[idx]);

    const float feat[6] = {s1, s2, s1t, s2t, cr, cl};
    float g[4];
#pragma unroll
    for (int o = 0; o < 4; ++o) g[o] = cb2[o];

#pragma unroll
    for (int c16 = 0; c16 < 16; ++c16) {
        float h = cb1[c16];
#pragma unroll
        for (int c = 0; c < 6; ++c) h = fmaf(feat[c], cw1[c16 * 6 + c], h);
        float targ = 0.7978845608028654f * (h + 0.044715f * h * h * h);
        targ = fminf(fmaxf(targ, -15.f), 15.f);
        float e2 = __expf(2.f * targ);
        float th = (e2 - 1.f) / (e2 + 1.f);
        float hid = 0.5f * h * (1.f + th);
#pragma unroll
        for (int o = 0; o < 4; ++o) g[o] = fmaf(hid, cw2[o * 16 + c16], g[o]);
    }
#pragma unroll
    for (int o = 0; o < 4; ++o) g[o] = 1.f / (1.f + __expf(-g[o]));

    const float mx = fmaxf(s1, s2);
    const float lae = mx + __logf(1.f + __expf(-fabsf(s1 - s2)));
    Smix[idx] = s1 + g[0] * s2 + g[1] * (lae - s1) - g[2] * (BETA_NOT * s2) + g[3] * cr;
}

// ---------------------------------------------------------------------------
// y = y_base + sigmoid(chain)*y_chain, (b,h,n,dk) -> (b,n,h*dk)
// ---------------------------------------------------------------------------
__global__ __launch_bounds__(256) void combine_y(
    const float* __restrict__ y1, const float* __restrict__ y2,
    const float* __restrict__ smallf, float* __restrict__ y)
{
    const long i = (long)blockIdx.x * 256 + threadIdx.x;
    const int dk = (int)(i & 63);
    const long t = i >> 6;
    const int n = (int)(t % Nc);
    const long t2 = t / Nc;
    const int h = (int)(t2 & 7);
    const int b = (int)(t2 >> 3);
    const float w = 1.f / (1.f + __expf(-smallf[180]));
    const float v = y1[i] + w * y2[i];
    y[((long)(b * Nc + n)) * Dc + h * DKc + dk] = v;
}

// Final store: bf16 or fp32 per sniffed input dtype.
__global__ __launch_bounds__(256) void store_out(
    const float* __restrict__ yo, const void* xraw, void* out)
{
    const int is32 = sniff_is_fp32(xraw);
    const long i = (long)blockIdx.x * 256 + threadIdx.x;
    if (i < (long)Bc * Nc * Dc) {
        if (is32) ((float*)out)[i] = yo[i];
        else      ((bf16*)out)[i] = __float2bfloat16(yo[i]);
    }
}

// ---------------------------------------------------------------------------
extern "C" void kernel_launch(void* const* d_in, const int* in_sizes, int n_in,
                              void* d_out, int out_size, void* d_ws, size_t ws_size,
                              hipStream_t stream)
{
    const size_t HD   = (size_t)BHc * Nc * DKc;   // 786432
    const size_t MAT  = (size_t)Nc * Nc;          // 589824
    const size_t MATS = (size_t)BHc * MAT;        // 9437184

    // ---- workspace budget (floats) ----
    float* ws = (float*)d_ws;
    size_t off = 0;
    auto alloc = [&](size_t n) { float* p = ws + off; off += n; return p; };

    float* xf     = alloc(HD);
    float* w1f    = alloc(HD);
    float* w2f    = alloc(HD);
    float* pwf    = alloc((size_t)Dc * Dc);
    float* smallf = alloc(192);
    float* q1 = alloc(HD); float* k1 = alloc(HD); float* v1 = alloc(HD);
    float* q2 = alloc(HD); float* k2 = alloc(HD); float* v2 = alloc(HD);
    float* S1   = alloc(MATS);
    float* S2   = alloc(MATS);
    float* Smix = alloc(MATS);
    bf16* A1b = (bf16*)alloc(MATS / 2);
    bf16* A2b = (bf16*)alloc(MATS / 2);
    bf16* Crb = (bf16*)alloc(MATS / 2);
    bf16* Clb = (bf16*)alloc(MATS / 2);
    float* tr  = alloc(HD);
    float* yb1 = alloc(HD);
    float* yb2 = alloc(HD);
    float* yc  = alloc(HD);
    float* yout = alloc(HD);

    const size_t NEED_BYTES = off * sizeof(float);   // = 233,833,216
    if (ws_size < NEED_BYTES) {
        fill_sentinel<<<dim3(3072), 256, 0, stream>>>((unsigned short*)d_out);
        return;
    }

    // 0. normalize inputs to fp32 (dtype sniffed on device)
    convert_inputs<<<dim3(3072), 256, 0, stream>>>(
        d_in[0], d_in[1], d_in[2], d_in[3], d_in[4], d_in[5], d_in[6], d_in[7],
        d_in[8], xf, w1f, w2f, pwf, smallf);

    // 1. QKV projections
    gemm_qkv<<<dim3(24, 24, 1), 256, 0, stream>>>(xf, w1f, q1, k1, v1);
    gemm_qkv<<<dim3(24, 24, 1), 256, 0, stream>>>(xf, w2f, q2, k2, v2);

    // 2. S = scale * q @ k^T per head
    gemm_tile<float, float, float, true, 0><<<dim3(12, 12, BHc), 256, 0, stream>>>(
        q1, k1, S1, Nc, Nc, DKc, DKc, DKc, Nc, (long)Nc * DKc, (long)Nc * DKc, (long)MAT, SCALE);
    gemm_tile<float, float, float, true, 0><<<dim3(12, 12, BHc), 256, 0, stream>>>(
        q2, k2, S2, Nc, Nc, DKc, DKc, DKc, Nc, (long)Nc * DKc, (long)Nc * DKc, (long)MAT, SCALE);

    // 3. A1/A2 = softmax(S) -> bf16
    softmax_rows<bf16><<<BHc * Nc, 256, 0, stream>>>(S1, A1b);
    softmax_rows<bf16><<<BHc * Nc, 256, 0, stream>>>(S2, A2b);

    // 4. Cr = log(A1@A2+eps), Cl = log(A2@A1+eps)  (bf16 in/out, fp32 acc)
    gemm_tile<bf16, bf16, bf16, false, 1><<<dim3(12, 12, BHc), 256, 0, stream>>>(
        A1b, A2b, Crb, Nc, Nc, Nc, Nc, Nc, Nc, (long)MAT, (long)MAT, (long)MAT, 1.f);
    gemm_tile<bf16, bf16, bf16, false, 1><<<dim3(12, 12, BHc), 256, 0, stream>>>(
        A2b, A1b, Clb, Nc, Nc, Nc, Nc, Nc, Nc, (long)MAT, (long)MAT, (long)MAT, 1.f);

    // 5. gates + Smix (fp32 logits)
    gates_smix<<<dim3(48, 48, BHc), 256, 0, stream>>>(S1, S2, Crb, Clb, Smix, smallf);

    // 6. A = softmax(Smix) in place (fp32)
    softmax_rows<float><<<BHc * Nc, 256, 0, stream>>>(Smix, Smix);

    // 7. transport = A2 @ v2
    gemm_tile<bf16, float, float, false, 0><<<dim3(1, 12, BHc), 256, 0, stream>>>(
        A2b, v2, tr, Nc, DKc, Nc, Nc, DKc, DKc, (long)MAT, (long)Nc * DKc, (long)Nc * DKc, 1.f);

    // 8. y_base = A @ v1 ; y_chain = A1 @ transport
    gemm_tile<float, float, float, false, 0><<<dim3(1, 12, BHc), 256, 0, stream>>>(
        Smix, v1, yb1, Nc, DKc, Nc, Nc, DKc, DKc, (long)MAT, (long)Nc * DKc, (long)Nc * DKc, 1.f);
    gemm_tile<bf16, float, float, false, 0><<<dim3(1, 12, BHc), 256, 0, stream>>>(
        A1b, tr, yb2, Nc, DKc, Nc, Nc, DKc, DKc, (long)MAT, (long)Nc * DKc, (long)Nc * DKc, 1.f);

    // 9. combine + layout to (B,N,D)
    combine_y<<<dim3(3072), 256, 0, stream>>>(yb1, yb2, smallf, yc);

    // 10. proj -> fp32 temp, then dtype-aware store
    gemm_tile<float, float, float, false, 0><<<dim3(8, 24, 1), 256, 0, stream>>>(
        yc, pwf, yout, Bc * Nc, Dc, Dc, Dc, Dc, Dc, 0, 0, 0, 1.f);
    store_out<<<dim3(3072), 256, 0, stream>>>(yout, d_in[0], d_out);
}

// Round 3
// 732.786 us; speedup vs baseline: 1.3709x; 1.3709x over previous
//
#include <hip/hip_runtime.h>
#include <hip/hip_bf16.h>
#include <math.h>

typedef __hip_bfloat16 bf16;
typedef __attribute__((ext_vector_type(8))) short short8;   // 8 bf16 (4 VGPRs)
typedef __attribute__((ext_vector_type(4))) float f32x4;
#define DEVINL __device__ __forceinline__

constexpr int Bc  = 2;
constexpr int Nc  = 768;
constexpr int Dc  = 512;
constexpr int Hc  = 8;
constexpr int DKc = 64;
constexpr int BHc = Bc * Hc;
constexpr float SCALE    = 0.125f;   // 1/sqrt(64)
constexpr float EPSF     = 1e-6f;
constexpr float BETA_NOT = 0.5f;

DEVINL float ldf(const float* p, long i) { return p[i]; }
DEVINL float ldf(const bf16* p, long i) { return __bfloat162float(p[i]); }
DEVINL void stf(float* p, long i, float v) { p[i] = v; }
DEVINL void stf(bf16* p, long i, float v) { p[i] = __float2bfloat16(v); }

// ---------------------------------------------------------------------------
// Dtype sniffer (see round 1 notes): bf16-decode of fp32 bit patterns blows
// past 1000 with overwhelming probability. Deterministic per launch.
// ---------------------------------------------------------------------------
DEVINL int sniff_is_fp32(const void* xraw) {
    const unsigned short* p = (const unsigned short*)xraw;
    float mx = 0.f;
#pragma unroll 1
    for (int j = 0; j < 128; ++j) {
        float v = __uint_as_float(((unsigned)p[j]) << 16);
        mx = fmaxf(mx, fabsf(v));
    }
    return mx > 1000.f ? 1 : 0;
}

DEVINL float cvt_elem(const void* s, long j, int is32) {
    return is32 ? ((const float*)s)[j]
                : __bfloat162float(((const bf16*)s)[j]);
}

__global__ __launch_bounds__(256) void convert_inputs(
    const void* x, const void* w1, const void* w2, const void* pw,
    const void* c1w, const void* c1b, const void* c2w, const void* c2b,
    const void* ch,
    float* xf, float* w1f, float* w2f, float* pwf, float* smallf)
{
    const int is32 = sniff_is_fp32(x);
    const long i = (long)blockIdx.x * 256 + threadIdx.x;
    if (i < (long)Bc * Nc * Dc) {
        xf[i]  = cvt_elem(x,  i, is32);
        w1f[i] = cvt_elem(w1, i, is32);
        w2f[i] = cvt_elem(w2, i, is32);
    }
    if (i < (long)Dc * Dc) pwf[i] = cvt_elem(pw, i, is32);
    if (i < 96)       smallf[i] = cvt_elem(c1w, i,        is32);
    else if (i < 112) smallf[i] = cvt_elem(c1b, i - 96,   is32);
    else if (i < 176) smallf[i] = cvt_elem(c2w, i - 112,  is32);
    else if (i < 180) smallf[i] = cvt_elem(c2b, i - 176,  is32);
    else if (i == 180) smallf[180] = cvt_elem(ch, 0, is32);
}

__global__ __launch_bounds__(256) void fill_sentinel(unsigned short* o) {
    const long i = (long)blockIdx.x * 256 + threadIdx.x;
    if (i < (long)Bc * Nc * Dc) o[i] = 0x40E0;  // bf16 7.0
}

// ---------------------------------------------------------------------------
// Batched bf16 transpose, 64x64 tiles. dst[n][m] = src[m][n], per 768x768 mat.
// ---------------------------------------------------------------------------
__global__ __launch_bounds__(256) void transpose_bf16(
    const unsigned short* __restrict__ src, unsigned short* __restrict__ dst)
{
    __shared__ unsigned short tile[64][68];
    const long base = (long)blockIdx.z * Nc * Nc;
    const int r0 = blockIdx.y * 64, c0 = blockIdx.x * 64;
    const int t = threadIdx.x;
    const int lr = t >> 4, lc4 = (t & 15) * 4;
#pragma unroll
    for (int i = 0; i < 4; ++i) {
        int r = lr + i * 16;
        *(uint2*)&tile[r][lc4] =
            *(const uint2*)&src[base + (long)(r0 + r) * Nc + c0 + lc4];
    }
    __syncthreads();
#pragma unroll
    for (int i = 0; i < 4; ++i) {
        int r = lr + i * 16;   // row of dst within the c-tile
        unsigned short v[4];
#pragma unroll
        for (int j = 0; j < 4; ++j) v[j] = tile[lc4 + j][r];
        *(uint2*)&dst[base + (long)(c0 + r) * Nc + r0 + lc4] = *(uint2*)v;
    }
}

// ---------------------------------------------------------------------------
// MFMA bf16 NT GEMM: C = A (M,K) @ B^T(stored (N,K)), batched via blockIdx.z.
// 128x128 tile, BK=32, 256 threads = 4 waves in 2x2 quadrants, each wave 4x4
// tiles of v_mfma_f32_16x16x32_bf16. LDS rows padded to 40 bf16 (80 B =
// 5*16 B: ds_read_b128 stays 16B-aligned; 20-bank stride -> 2-way only).
// EPI: 0 plain bf16 store, 1 log(max(x,0)+eps) bf16 store.
// Requires M%128==0, N%128==0, K%32==0.
// ---------------------------------------------------------------------------
template <int EPI>
__global__ __launch_bounds__(256) void gemm_nt_mfma(
    const bf16* __restrict__ Ag, const bf16* __restrict__ Btg,
    bf16* __restrict__ Cg, int M, int N, int K,
    long sA, long sB, long sC, float alpha)
{
    __shared__ unsigned short Asm[128 * 40];
    __shared__ unsigned short Bsm[128 * 40];

    const int tid  = threadIdx.x;
    const int wave = tid >> 6;
    const int lane = tid & 63;
    const int q    = lane >> 4;     // quad
    const int ln   = lane & 15;
    const int wm   = wave & 1;      // m-half of the 128x128 tile
    const int wn   = wave >> 1;     // n-half

    const bf16* A  = Ag  + (long)blockIdx.z * sA + (long)(blockIdx.y * 128) * K;
    const bf16* Bt = Btg + (long)blockIdx.z * sB + (long)(blockIdx.x * 128) * K;
    bf16*       C  = Cg  + (long)blockIdx.z * sC;

    // staging: 512 16B-chunks per tile; thread handles chunks tid and tid+256
    const int r_s0 = tid >> 2, c_s = tid & 3;     // rows 0..63
    const int r_s1 = r_s0 + 64;                   // rows 64..127
    const bf16* pa0 = A  + (long)r_s0 * K + c_s * 8;
    const bf16* pa1 = A  + (long)r_s1 * K + c_s * 8;
    const bf16* pb0 = Bt + (long)r_s0 * K + c_s * 8;
    const bf16* pb1 = Bt + (long)r_s1 * K + c_s * 8;
    const int w_s0 = r_s0 * 40 + c_s * 8;         // ushort units
    const int w_s1 = r_s1 * 40 + c_s * 8;

    f32x4 acc[4][4];
#pragma unroll
    for (int i = 0; i < 4; ++i)
#pragma unroll
        for (int j = 0; j < 4; ++j)
            acc[i][j] = (f32x4){0.f, 0.f, 0.f, 0.f};

    for (int k0 = 0; k0 < K; k0 += 32) {
        const uint4 va0 = *(const uint4*)(pa0 + k0);
        const uint4 va1 = *(const uint4*)(pa1 + k0);
        const uint4 vb0 = *(const uint4*)(pb0 + k0);
        const uint4 vb1 = *(const uint4*)(pb1 + k0);
        __syncthreads();   // previous iteration's frag reads complete
        *(uint4*)&Asm[w_s0] = va0;
        *(uint4*)&Asm[w_s1] = va1;
        *(uint4*)&Bsm[w_s0] = vb0;
        *(uint4*)&Bsm[w_s1] = vb1;
        __syncthreads();

        short8 af[4], bf[4];
#pragma unroll
        for (int mt = 0; mt < 4; ++mt) {
            int m = wm * 64 + mt * 16 + ln;
            af[mt] = *(const short8*)&Asm[m * 40 + q * 8];
        }
#pragma unroll
        for (int nt = 0; nt < 4; ++nt) {
            int n = wn * 64 + nt * 16 + ln;
            bf[nt] = *(const short8*)&Bsm[n * 40 + q * 8];
        }
#pragma unroll
        for (int mt = 0; mt < 4; ++mt)
#pragma unroll
            for (int nt = 0; nt < 4; ++nt)
                acc[mt][nt] = __builtin_amdgcn_mfma_f32_16x16x32_bf16(
                    af[mt], bf[nt], acc[mt][nt], 0, 0, 0);
    }

    // C/D layout: col = lane&15, row = quad*4 + reg   [m89/m91 verified]
#pragma unroll
    for (int mt = 0; mt < 4; ++mt) {
#pragma unroll
        for (int nt = 0; nt < 4; ++nt) {
            const int col = blockIdx.x * 128 + wn * 64 + nt * 16 + ln;
            const int rowb = blockIdx.y * 128 + wm * 64 + mt * 16 + q * 4;
#pragma unroll
            for (int r = 0; r < 4; ++r) {
                float v = acc[mt][nt][r] * alpha;
                if (EPI == 1) v = __logf(fmaxf(v, 0.f) + EPSF);
                C[(long)(rowb + r) * N + col] = __float2bfloat16(v);
            }
        }
    }
}

// ---------------------------------------------------------------------------
// Generic fp32 64x64-tile GEMM (unchanged from round 2).
// ---------------------------------------------------------------------------
template <typename TA, typename TB, typename TC, bool TRANS_B, int EPI>
__global__ __launch_bounds__(256) void gemm_tile(
    const TA* __restrict__ Ag, const TB* __restrict__ Bg, TC* __restrict__ Cg,
    int M, int Nm, int K, int lda, int ldb, int ldc,
    long sA, long sB, long sC, float alpha)
{
    __shared__ float As[16][68];
    __shared__ float Bs[16][68];

    const int bz = blockIdx.z;
    const TA* A = Ag + (long)bz * sA;
    const TB* B = Bg + (long)bz * sB;
    TC*       C = Cg + (long)bz * sC;

    const int r0 = blockIdx.y * 64;
    const int c0 = blockIdx.x * 64;
    const int tid = threadIdx.x;
    const int tx = tid & 15, ty = tid >> 4;

    float acc[4][4] = {};

    for (int k0 = 0; k0 < K; k0 += 16) {
        {
            int kk = tid & 15;
            int rbase = tid >> 4;
#pragma unroll
            for (int i = 0; i < 4; ++i) {
                int row = rbase + i * 16;
                As[kk][row] = ldf(A, (long)(r0 + row) * lda + k0 + kk);
            }
        }
        if (!TRANS_B) {
            int cc = tid & 63;
            int kb = tid >> 6;
#pragma unroll
            for (int i = 0; i < 4; ++i) {
                int kk = kb + i * 4;
                Bs[kk][cc] = ldf(B, (long)(k0 + kk) * ldb + c0 + cc);
            }
        } else {
            int kk = tid & 15;
            int cb = tid >> 4;
#pragma unroll
            for (int i = 0; i < 4; ++i) {
                int cc = cb + i * 16;
                Bs[kk][cc] = ldf(B, (long)(c0 + cc) * ldb + k0 + kk);
            }
        }
        __syncthreads();
#pragma unroll
        for (int kk = 0; kk < 16; ++kk) {
            float4 a4 = *(const float4*)&As[kk][ty * 4];
            float4 b4 = *(const float4*)&Bs[kk][tx * 4];
            float av[4] = {a4.x, a4.y, a4.z, a4.w};
            float bv[4] = {b4.x, b4.y, b4.z, b4.w};
#pragma unroll
            for (int i = 0; i < 4; ++i)
#pragma unroll
                for (int j = 0; j < 4; ++j)
                    acc[i][j] = fmaf(av[i], bv[j], acc[i][j]);
        }
        __syncthreads();
    }

#pragma unroll
    for (int i = 0; i < 4; ++i) {
        int row = r0 + ty * 4 + i;
#pragma unroll
        for (int j = 0; j < 4; ++j) {
            int col = c0 + tx * 4 + j;
            float v = acc[i][j] * alpha;
            if (EPI == 1) v = __logf(fmaxf(v, 0.f) + EPSF);
            stf(C, (long)row * ldc + col, v);
        }
    }
}

// ---------------------------------------------------------------------------
// QKV projection (unchanged).
// ---------------------------------------------------------------------------
__global__ __launch_bounds__(256) void gemm_qkv(
    const float* __restrict__ X, const float* __restrict__ W,
    float* __restrict__ Q, float* __restrict__ Ko, float* __restrict__ V)
{
    __shared__ float As[16][68];
    __shared__ float Bs[16][68];
    const int r0 = blockIdx.y * 64;
    const int c0 = blockIdx.x * 64;
    const int tid = threadIdx.x;
    const int tx = tid & 15, ty = tid >> 4;

    float acc[4][4] = {};

    for (int k0 = 0; k0 < Dc; k0 += 16) {
        {
            int kk = tid & 15;
            int rbase = tid >> 4;
#pragma unroll
            for (int i = 0; i < 4; ++i) {
                int row = rbase + i * 16;
                As[kk][row] = X[(long)(r0 + row) * Dc + k0 + kk];
            }
        }
        {
            int cc = tid & 63;
            int kb = tid >> 6;
#pragma unroll
            for (int i = 0; i < 4; ++i) {
                int kk = kb + i * 4;
                Bs[kk][cc] = W[(long)(k0 + kk) * (3 * Dc) + c0 + cc];
            }
        }
        __syncthreads();
#pragma unroll
        for (int kk = 0; kk < 16; ++kk) {
            float4 a4 = *(const float4*)&As[kk][ty * 4];
            float4 b4 = *(const float4*)&Bs[kk][tx * 4];
            float av[4] = {a4.x, a4.y, a4.z, a4.w};
            float bv[4] = {b4.x, b4.y, b4.z, b4.w};
#pragma unroll
            for (int i = 0; i < 4; ++i)
#pragma unroll
                for (int j = 0; j < 4; ++j)
                    acc[i][j] = fmaf(av[i], bv[j], acc[i][j]);
        }
        __syncthreads();
    }

#pragma unroll
    for (int i = 0; i < 4; ++i) {
        int row = r0 + ty * 4 + i;
        int b = row >= Nc ? 1 : 0;
        int n = row - b * Nc;
        int cbase = c0 + tx * 4;
        int t = cbase >> 9;
        int h = (cbase & 511) >> 6;
        float* dst = (t == 0) ? Q : (t == 1) ? Ko : V;
        long base = (((long)b * Hc + h) * Nc + n) * DKc;
#pragma unroll
        for (int j = 0; j < 4; ++j) {
            int dk = (cbase + j) & 63;
            dst[base + dk] = acc[i][j];
        }
    }
}

// ---------------------------------------------------------------------------
// Row softmax over width 768 (unchanged).
// ---------------------------------------------------------------------------
template <typename TO>
__global__ __launch_bounds__(256) void softmax_rows(const float* src, TO* dst)
{
    __shared__ float red[4];
    const long row = blockIdx.x;
    const float* s = src + row * Nc;
    TO* d = dst + row * Nc;
    const int tid = threadIdx.x;

    float v[3];
    float m = -1e30f;
#pragma unroll
    for (int i = 0; i < 3; ++i) { v[i] = s[tid + i * 256]; m = fmaxf(m, v[i]); }

#pragma unroll
    for (int off = 32; off > 0; off >>= 1) m = fmaxf(m, __shfl_down(m, off, 64));
    if ((tid & 63) == 0) red[tid >> 6] = m;
    __syncthreads();
    if (tid == 0) {
        float mm = red[0];
        for (int w = 1; w < 4; ++w) mm = fmaxf(mm, red[w]);
        red[0] = mm;
    }
    __syncthreads();
    m = red[0];
    __syncthreads();

    float e[3];
    float sum = 0.f;
#pragma unroll
    for (int i = 0; i < 3; ++i) { e[i] = __expf(v[i] - m); sum += e[i]; }
#pragma unroll
    for (int off = 32; off > 0; off >>= 1) sum += __shfl_down(sum, off, 64);
    if ((tid & 63) == 0) red[tid >> 6] = sum;
    __syncthreads();
    if (tid == 0) red[0] = red[0] + red[1] + red[2] + red[3];
    __syncthreads();
    const float inv = 1.f / fmaxf(red[0], 1e-30f);
#pragma unroll
    for (int i = 0; i < 3; ++i) stf(d, tid + i * 256, e[i] * inv);
}

// ---------------------------------------------------------------------------
// Gate network + Smix (unchanged).
// ---------------------------------------------------------------------------
__global__ __launch_bounds__(256) void gates_smix(
    const float* __restrict__ S1g, const float* __restrict__ S2g,
    const bf16* __restrict__ Crg, const bf16* __restrict__ Clg,
    float* __restrict__ Smixg, const float* __restrict__ smallf)
{
    __shared__ float t1t[16][17], t2t[16][17];
    __shared__ float cs[192];

    const int bh = blockIdx.z;
    const long mat = (long)bh * Nc * Nc;
    const float* S1 = S1g + mat;
    const float* S2 = S2g + mat;
    const bf16*  Cr = Crg + mat;
    const bf16*  Cl = Clg + mat;
    float* Smix = Smixg + mat;

    const int tid = threadIdx.x;
    if (tid < 192) cs[tid] = smallf[tid];

    const int n0 = blockIdx.y * 16, m0 = blockIdx.x * 16;
    const int tx = tid & 15, ty = tid >> 4;

    t1t[ty][tx] = S1[(long)(m0 + ty) * Nc + n0 + tx];
    t2t[ty][tx] = S2[(long)(m0 + ty) * Nc + n0 + tx];
    __syncthreads();

    const float* cw1 = cs;       const float* cb1 = cs + 96;
    const float* cw2 = cs + 112; const float* cb2 = cs + 176;

    const int n = n0 + ty, mcol = m0 + tx;
    const long idx = (long)n * Nc + mcol;
    const float s1 = S1[idx], s2 = S2[idx];
    const float s1t = t1t[tx][ty], s2t = t2t[tx][ty];
    const float cr = __bfloat162float(Cr[idx]), cl = __bfloat162float(Cl[idx]);

    const float feat[6] = {s1, s2, s1t, s2t, cr, cl};
    float g[4];
#pragma unroll
    for (int o = 0; o < 4; ++o) g[o] = cb2[o];

#pragma unroll
    for (int c16 = 0; c16 < 16; ++c16) {
        float h = cb1[c16];
#pragma unroll
        for (int c = 0; c < 6; ++c) h = fmaf(feat[c], cw1[c16 * 6 + c], h);
        float targ = 0.7978845608028654f * (h + 0.044715f * h * h * h);
        targ = fminf(fmaxf(targ, -15.f), 15.f);
        float e2 = __expf(2.f * targ);
        float th = (e2 - 1.f) / (e2 + 1.f);
        float hid = 0.5f * h * (1.f + th);
#pragma unroll
        for (int o = 0; o < 4; ++o) g[o] = fmaf(hid, cw2[o * 16 + c16], g[o]);
    }
#pragma unroll
    for (int o = 0; o < 4; ++o) g[o] = 1.f / (1.f + __expf(-g[o]));

    const float mx = fmaxf(s1, s2);
    const float lae = mx + __logf(1.f + __expf(-fabsf(s1 - s2)));
    Smix[idx] = s1 + g[0] * s2 + g[1] * (lae - s1) - g[2] * (BETA_NOT * s2) + g[3] * cr;
}

// ---------------------------------------------------------------------------
__global__ __launch_bounds__(256) void combine_y(
    const float* __restrict__ y1, const float* __restrict__ y2,
    const float* __restrict__ smallf, float* __restrict__ y)
{
    const long i = (long)blockIdx.x * 256 + threadIdx.x;
    const int dk = (int)(i & 63);
    const long t = i >> 6;
    const int n = (int)(t % Nc);
    const long t2 = t / Nc;
    const int h = (int)(t2 & 7);
    const int b = (int)(t2 >> 3);
    const float w = 1.f / (1.f + __expf(-smallf[180]));
    const float v = y1[i] + w * y2[i];
    y[((long)(b * Nc + n)) * Dc + h * DKc + dk] = v;
}

__global__ __launch_bounds__(256) void store_out(
    const float* __restrict__ yo, const void* xraw, void* out)
{
    const int is32 = sniff_is_fp32(xraw);
    const long i = (long)blockIdx.x * 256 + threadIdx.x;
    if (i < (long)Bc * Nc * Dc) {
        if (is32) ((float*)out)[i] = yo[i];
        else      ((bf16*)out)[i] = __float2bfloat16(yo[i]);
    }
}

// ---------------------------------------------------------------------------
extern "C" void kernel_launch(void* const* d_in, const int* in_sizes, int n_in,
                              void* d_out, int out_size, void* d_ws, size_t ws_size,
                              hipStream_t stream)
{
    const size_t HD   = (size_t)BHc * Nc * DKc;   // 786432
    const size_t MAT  = (size_t)Nc * Nc;          // 589824
    const size_t MATS = (size_t)BHc * MAT;        // 9437184

    float* ws = (float*)d_ws;
    size_t off = 0;
    auto alloc = [&](size_t n) { float* p = ws + off; off += n; return p; };

    float* xf     = alloc(HD);
    float* w1f    = alloc(HD);
    float* w2f    = alloc(HD);
    float* pwf    = alloc((size_t)Dc * Dc);
    float* smallf = alloc(192);
    float* q1 = alloc(HD); float* k1 = alloc(HD); float* v1 = alloc(HD);
    float* q2 = alloc(HD); float* k2 = alloc(HD); float* v2 = alloc(HD);
    float* S1   = alloc(MATS);
    float* S2   = alloc(MATS);
    float* Smix = alloc(MATS);
    bf16* A1b = (bf16*)alloc(MATS / 2);
    bf16* A2b = (bf16*)alloc(MATS / 2);
    bf16* Crb = (bf16*)alloc(MATS / 2);
    bf16* Clb = (bf16*)alloc(MATS / 2);
    float* tr  = alloc(HD);
    float* yb1 = alloc(HD);
    float* yb2 = alloc(HD);
    float* yc  = alloc(HD);
    float* yout = alloc(HD);

    // Transposes alias Smix (dead until step 5; exactly 2*MATS bf16 = MATS fp32)
    bf16* A1tb = (bf16*)Smix;
    bf16* A2tb = ((bf16*)Smix) + MATS;

    const size_t NEED_BYTES = off * sizeof(float);
    if (ws_size < NEED_BYTES) {
        fill_sentinel<<<dim3(3072), 256, 0, stream>>>((unsigned short*)d_out);
        return;
    }

    // 0. normalize inputs to fp32
    convert_inputs<<<dim3(3072), 256, 0, stream>>>(
        d_in[0], d_in[1], d_in[2], d_in[3], d_in[4], d_in[5], d_in[6], d_in[7],
        d_in[8], xf, w1f, w2f, pwf, smallf);

    // 1. QKV projections
    gemm_qkv<<<dim3(24, 24, 1), 256, 0, stream>>>(xf, w1f, q1, k1, v1);
    gemm_qkv<<<dim3(24, 24, 1), 256, 0, stream>>>(xf, w2f, q2, k2, v2);

    // 2. S = scale * q @ k^T per head
    gemm_tile<float, float, float, true, 0><<<dim3(12, 12, BHc), 256, 0, stream>>>(
        q1, k1, S1, Nc, Nc, DKc, DKc, DKc, Nc, (long)Nc * DKc, (long)Nc * DKc, (long)MAT, SCALE);
    gemm_tile<float, float, float, true, 0><<<dim3(12, 12, BHc), 256, 0, stream>>>(
        q2, k2, S2, Nc, Nc, DKc, DKc, DKc, Nc, (long)Nc * DKc, (long)Nc * DKc, (long)MAT, SCALE);

    // 3. A1/A2 = softmax(S) -> bf16, then bf16 transposes (into Smix alias)
    softmax_rows<bf16><<<BHc * Nc, 256, 0, stream>>>(S1, A1b);
    softmax_rows<bf16><<<BHc * Nc, 256, 0, stream>>>(S2, A2b);
    transpose_bf16<<<dim3(12, 12, BHc), 256, 0, stream>>>(
        (const unsigned short*)A1b, (unsigned short*)A1tb);
    transpose_bf16<<<dim3(12, 12, BHc), 256, 0, stream>>>(
        (const unsigned short*)A2b, (unsigned short*)A2tb);

    // 4. Cr = log(A1@A2+eps), Cl = log(A2@A1+eps) via bf16 MFMA (NT layout)
    gemm_nt_mfma<1><<<dim3(6, 6, BHc), 256, 0, stream>>>(
        A1b, A2tb, Crb, Nc, Nc, Nc, (long)MAT, (long)MAT, (long)MAT, 1.f);
    gemm_nt_mfma<1><<<dim3(6, 6, BHc), 256, 0, stream>>>(
        A2b, A1tb, Clb, Nc, Nc, Nc, (long)MAT, (long)MAT, (long)MAT, 1.f);

    // 5. gates + Smix (overwrites the transpose aliases — they're dead now)
    gates_smix<<<dim3(48, 48, BHc), 256, 0, stream>>>(S1, S2, Crb, Clb, Smix, smallf);

    // 6. A = softmax(Smix) in place
    softmax_rows<float><<<BHc * Nc, 256, 0, stream>>>(Smix, Smix);

    // 7. transport = A2 @ v2
    gemm_tile<bf16, float, float, false, 0><<<dim3(1, 12, BHc), 256, 0, stream>>>(
        A2b, v2, tr, Nc, DKc, Nc, Nc, DKc, DKc, (long)MAT, (long)Nc * DKc, (long)Nc * DKc, 1.f);

    // 8. y_base = A @ v1 ; y_chain = A1 @ transport
    gemm_tile<float, float, float, false, 0><<<dim3(1, 12, BHc), 256, 0, stream>>>(
        Smix, v1, yb1, Nc, DKc, Nc, Nc, DKc, DKc, (long)MAT, (long)Nc * DKc, (long)Nc * DKc, 1.f);
    gemm_tile<bf16, float, float, false, 0><<<dim3(1, 12, BHc), 256, 0, stream>>>(
        A1b, tr, yb2, Nc, DKc, Nc, Nc, DKc, DKc, (long)MAT, (long)Nc * DKc, (long)Nc * DKc, 1.f);

    // 9. combine + layout
    combine_y<<<dim3(3072), 256, 0, stream>>>(yb1, yb2, smallf, yc);

    // 10. proj + dtype-aware store
    gemm_tile<float, float, float, false, 0><<<dim3(8, 24, 1), 256, 0, stream>>>(
        yc, pwf, yout, Bc * Nc, Dc, Dc, Dc, Dc, Dc, 0, 0, 0, 1.f);
    store_out<<<dim3(3072), 256, 0, stream>>>(yout, d_in[0], d_out);
}

// Round 4
// 652.357 us; speedup vs baseline: 1.5399x; 1.1233x over previous
//
#include <hip/hip_runtime.h>
#include <hip/hip_bf16.h>
#include <math.h>

typedef __hip_bfloat16 bf16;
typedef __attribute__((ext_vector_type(8))) short short8;   // 8 bf16 (4 VGPRs)
typedef __attribute__((ext_vector_type(4))) float f32x4;
#define DEVINL __device__ __forceinline__

constexpr int Bc  = 2;
constexpr int Nc  = 768;
constexpr int Dc  = 512;
constexpr int Hc  = 8;
constexpr int DKc = 64;
constexpr int BHc = Bc * Hc;
constexpr float SCALE    = 0.125f;   // 1/sqrt(64)
constexpr float EPSF     = 1e-6f;
constexpr float BETA_NOT = 0.5f;

DEVINL float ldf(const float* p, long i) { return p[i]; }
DEVINL float ldf(const bf16* p, long i) { return __bfloat162float(p[i]); }
DEVINL void stf(float* p, long i, float v) { p[i] = v; }
DEVINL void stf(bf16* p, long i, float v) { p[i] = __float2bfloat16(v); }

DEVINL float sigf(float x) { return __fdividef(1.f, 1.f + __expf(-x)); }

// ---------------------------------------------------------------------------
// Dtype sniffer (round-1 notes): bf16-decode of fp32 bit patterns blows past
// 1000 with overwhelming probability. Deterministic per launch.
// ---------------------------------------------------------------------------
DEVINL int sniff_is_fp32(const void* xraw) {
    const unsigned short* p = (const unsigned short*)xraw;
    float mx = 0.f;
#pragma unroll 1
    for (int j = 0; j < 128; ++j) {
        float v = __uint_as_float(((unsigned)p[j]) << 16);
        mx = fmaxf(mx, fabsf(v));
    }
    return mx > 1000.f ? 1 : 0;
}

DEVINL float cvt_elem(const void* s, long j, int is32) {
    return is32 ? ((const float*)s)[j]
                : __bfloat162float(((const bf16*)s)[j]);
}

// Normalize inputs: x/w1/w2 -> bf16 copies (exact if already bf16),
// proj_w -> fp32, gate params -> fp32.
__global__ __launch_bounds__(256) void convert_all(
    const void* x, const void* w1, const void* w2, const void* pw,
    const void* c1w, const void* c1b, const void* c2w, const void* c2b,
    const void* ch,
    bf16* xb, bf16* w1b, bf16* w2b, float* pwf, float* smallf)
{
    const int is32 = sniff_is_fp32(x);
    const long i = (long)blockIdx.x * 256 + threadIdx.x;
    if (i < (long)Bc * Nc * Dc) {
        xb[i]  = __float2bfloat16(cvt_elem(x,  i, is32));
        w1b[i] = __float2bfloat16(cvt_elem(w1, i, is32));
        w2b[i] = __float2bfloat16(cvt_elem(w2, i, is32));
    }
    if (i < (long)Dc * Dc) pwf[i] = cvt_elem(pw, i, is32);
    if (i < 96)       smallf[i] = cvt_elem(c1w, i,        is32);
    else if (i < 112) smallf[i] = cvt_elem(c1b, i - 96,   is32);
    else if (i < 176) smallf[i] = cvt_elem(c2w, i - 112,  is32);
    else if (i < 180) smallf[i] = cvt_elem(c2b, i - 176,  is32);
    else if (i == 180) smallf[180] = cvt_elem(ch, 0, is32);
}

__global__ __launch_bounds__(256) void fill_sentinel(unsigned short* o) {
    const long i = (long)blockIdx.x * 256 + threadIdx.x;
    if (i < (long)Bc * Nc * Dc) o[i] = 0x40E0;  // bf16 7.0
}

// ---------------------------------------------------------------------------
// Generic bf16 transpose, 64x64 tiles: dst[c][r] = src[r][c]; src is (R,C).
// Batched via blockIdx.z with element strides sS/sD.
// ---------------------------------------------------------------------------
__global__ __launch_bounds__(256) void transpose_bf16(
    const unsigned short* __restrict__ src, unsigned short* __restrict__ dst,
    int R, int C, long sS, long sD)
{
    __shared__ unsigned short tile[64][68];
    const unsigned short* s = src + (long)blockIdx.z * sS;
    unsigned short* d = dst + (long)blockIdx.z * sD;
    const int r0 = blockIdx.y * 64, c0 = blockIdx.x * 64;
    const int t = threadIdx.x;
    const int lr = t >> 4, lc4 = (t & 15) * 4;
#pragma unroll
    for (int i = 0; i < 4; ++i) {
        int r = lr + i * 16;
        *(uint2*)&tile[r][lc4] = *(const uint2*)&s[(long)(r0 + r) * C + c0 + lc4];
    }
    __syncthreads();
#pragma unroll
    for (int i = 0; i < 4; ++i) {
        int r = lr + i * 16;
        unsigned short v[4];
#pragma unroll
        for (int j = 0; j < 4; ++j) v[j] = tile[lc4 + j][r];
        *(uint2*)&d[(long)(c0 + r) * R + r0 + lc4] = *(uint2*)v;
    }
}

// ---------------------------------------------------------------------------
// MFMA bf16 NT GEMM (validated round 3): C = A(M,K) @ B^T(stored (N,K)).
// 128x128 tile, BK=32, 4 waves 2x2, 4x4 16x16x32 tiles/wave. TC templated.
// ---------------------------------------------------------------------------
template <int EPI, typename TC>
__global__ __launch_bounds__(256) void gemm_nt_mfma(
    const bf16* __restrict__ Ag, const bf16* __restrict__ Btg,
    TC* __restrict__ Cg, int M, int N, int K,
    long sA, long sB, long sC, float alpha)
{
    __shared__ unsigned short Asm[128 * 40];
    __shared__ unsigned short Bsm[128 * 40];

    const int tid  = threadIdx.x;
    const int wave = tid >> 6;
    const int lane = tid & 63;
    const int q    = lane >> 4;
    const int ln   = lane & 15;
    const int wm   = wave & 1;
    const int wn   = wave >> 1;

    const bf16* A  = Ag  + (long)blockIdx.z * sA + (long)(blockIdx.y * 128) * K;
    const bf16* Bt = Btg + (long)blockIdx.z * sB + (long)(blockIdx.x * 128) * K;
    TC*         C  = Cg  + (long)blockIdx.z * sC;

    const int r_s0 = tid >> 2, c_s = tid & 3;
    const int r_s1 = r_s0 + 64;
    const bf16* pa0 = A  + (long)r_s0 * K + c_s * 8;
    const bf16* pa1 = A  + (long)r_s1 * K + c_s * 8;
    const bf16* pb0 = Bt + (long)r_s0 * K + c_s * 8;
    const bf16* pb1 = Bt + (long)r_s1 * K + c_s * 8;
    const int w_s0 = r_s0 * 40 + c_s * 8;
    const int w_s1 = r_s1 * 40 + c_s * 8;

    f32x4 acc[4][4];
#pragma unroll
    for (int i = 0; i < 4; ++i)
#pragma unroll
        for (int j = 0; j < 4; ++j)
            acc[i][j] = (f32x4){0.f, 0.f, 0.f, 0.f};

    for (int k0 = 0; k0 < K; k0 += 32) {
        const uint4 va0 = *(const uint4*)(pa0 + k0);
        const uint4 va1 = *(const uint4*)(pa1 + k0);
        const uint4 vb0 = *(const uint4*)(pb0 + k0);
        const uint4 vb1 = *(const uint4*)(pb1 + k0);
        __syncthreads();
        *(uint4*)&Asm[w_s0] = va0;
        *(uint4*)&Asm[w_s1] = va1;
        *(uint4*)&Bsm[w_s0] = vb0;
        *(uint4*)&Bsm[w_s1] = vb1;
        __syncthreads();

        short8 af[4], bfr[4];
#pragma unroll
        for (int mt = 0; mt < 4; ++mt) {
            int m = wm * 64 + mt * 16 + ln;
            af[mt] = *(const short8*)&Asm[m * 40 + q * 8];
        }
#pragma unroll
        for (int nt = 0; nt < 4; ++nt) {
            int n = wn * 64 + nt * 16 + ln;
            bfr[nt] = *(const short8*)&Bsm[n * 40 + q * 8];
        }
#pragma unroll
        for (int mt = 0; mt < 4; ++mt)
#pragma unroll
            for (int nt = 0; nt < 4; ++nt)
                acc[mt][nt] = __builtin_amdgcn_mfma_f32_16x16x32_bf16(
                    af[mt], bfr[nt], acc[mt][nt], 0, 0, 0);
    }

#pragma unroll
    for (int mt = 0; mt < 4; ++mt) {
#pragma unroll
        for (int nt = 0; nt < 4; ++nt) {
            const int col = blockIdx.x * 128 + wn * 64 + nt * 16 + ln;
            const int rowb = blockIdx.y * 128 + wm * 64 + mt * 16 + q * 4;
#pragma unroll
            for (int r = 0; r < 4; ++r) {
                float v = acc[mt][nt][r] * alpha;
                if (EPI == 1) v = __logf(fmaxf(v, 0.f) + EPSF);
                stf(C, (long)(rowb + r) * N + col, v);
            }
        }
    }
}

// ---------------------------------------------------------------------------
// QKV via MFMA: X(1536,512)bf16 @ Wt(1536,512)bf16 -> scatter fp32 q/k/v
// (B,H,N,DK). Same engine as gemm_nt_mfma, scatter epilogue.
// ---------------------------------------------------------------------------
__global__ __launch_bounds__(256) void qkv_mfma(
    const bf16* __restrict__ X, const bf16* __restrict__ Wt,
    float* __restrict__ Q, float* __restrict__ Ko, float* __restrict__ V)
{
    constexpr int K = Dc;  // 512
    __shared__ unsigned short Asm[128 * 40];
    __shared__ unsigned short Bsm[128 * 40];

    const int tid  = threadIdx.x;
    const int wave = tid >> 6;
    const int lane = tid & 63;
    const int q    = lane >> 4;
    const int ln   = lane & 15;
    const int wm   = wave & 1;
    const int wn   = wave >> 1;

    const bf16* A  = X  + (long)(blockIdx.y * 128) * K;
    const bf16* Bt = Wt + (long)(blockIdx.x * 128) * K;

    const int r_s0 = tid >> 2, c_s = tid & 3;
    const int r_s1 = r_s0 + 64;
    const bf16* pa0 = A  + (long)r_s0 * K + c_s * 8;
    const bf16* pa1 = A  + (long)r_s1 * K + c_s * 8;
    const bf16* pb0 = Bt + (long)r_s0 * K + c_s * 8;
    const bf16* pb1 = Bt + (long)r_s1 * K + c_s * 8;
    const int w_s0 = r_s0 * 40 + c_s * 8;
    const int w_s1 = r_s1 * 40 + c_s * 8;

    f32x4 acc[4][4];
#pragma unroll
    for (int i = 0; i < 4; ++i)
#pragma unroll
        for (int j = 0; j < 4; ++j)
            acc[i][j] = (f32x4){0.f, 0.f, 0.f, 0.f};

    for (int k0 = 0; k0 < K; k0 += 32) {
        const uint4 va0 = *(const uint4*)(pa0 + k0);
        const uint4 va1 = *(const uint4*)(pa1 + k0);
        const uint4 vb0 = *(const uint4*)(pb0 + k0);
        const uint4 vb1 = *(const uint4*)(pb1 + k0);
        __syncthreads();
        *(uint4*)&Asm[w_s0] = va0;
        *(uint4*)&Asm[w_s1] = va1;
        *(uint4*)&Bsm[w_s0] = vb0;
        *(uint4*)&Bsm[w_s1] = vb1;
        __syncthreads();

        short8 af[4], bfr[4];
#pragma unroll
        for (int mt = 0; mt < 4; ++mt) {
            int m = wm * 64 + mt * 16 + ln;
            af[mt] = *(const short8*)&Asm[m * 40 + q * 8];
        }
#pragma unroll
        for (int nt = 0; nt < 4; ++nt) {
            int n = wn * 64 + nt * 16 + ln;
            bfr[nt] = *(const short8*)&Bsm[n * 40 + q * 8];
        }
#pragma unroll
        for (int mt = 0; mt < 4; ++mt)
#pragma unroll
            for (int nt = 0; nt < 4; ++nt)
                acc[mt][nt] = __builtin_amdgcn_mfma_f32_16x16x32_bf16(
                    af[mt], bfr[nt], acc[mt][nt], 0, 0, 0);
    }

    // scatter: row -> (b, n); col (0..1535) -> (t, h, dk)
#pragma unroll
    for (int mt = 0; mt < 4; ++mt) {
#pragma unroll
        for (int nt = 0; nt < 4; ++nt) {
            const int col  = blockIdx.x * 128 + wn * 64 + nt * 16 + ln;
            const int rowb = blockIdx.y * 128 + wm * 64 + mt * 16 + q * 4;
            const int t = col >> 9;
            const int h = (col >> 6) & 7;
            const int dk = col & 63;
            float* dst = (t == 0) ? Q : (t == 1) ? Ko : V;
#pragma unroll
            for (int r = 0; r < 4; ++r) {
                const int row = rowb + r;
                const int b = row >= Nc ? 1 : 0;
                const int n = row - b * Nc;
                dst[(((long)b * Hc + h) * Nc + n) * DKc + dk] = acc[mt][nt][r];
            }
        }
    }
}

// ---------------------------------------------------------------------------
// Generic fp32 64x64-tile GEMM (unchanged, validated).
// ---------------------------------------------------------------------------
template <typename TA, typename TB, typename TC, bool TRANS_B, int EPI>
__global__ __launch_bounds__(256) void gemm_tile(
    const TA* __restrict__ Ag, const TB* __restrict__ Bg, TC* __restrict__ Cg,
    int M, int Nm, int K, int lda, int ldb, int ldc,
    long sA, long sB, long sC, float alpha)
{
    __shared__ float As[16][68];
    __shared__ float Bs[16][68];

    const int bz = blockIdx.z;
    const TA* A = Ag + (long)bz * sA;
    const TB* B = Bg + (long)bz * sB;
    TC*       C = Cg + (long)bz * sC;

    const int r0 = blockIdx.y * 64;
    const int c0 = blockIdx.x * 64;
    const int tid = threadIdx.x;
    const int tx = tid & 15, ty = tid >> 4;

    float acc[4][4] = {};

    for (int k0 = 0; k0 < K; k0 += 16) {
        {
            int kk = tid & 15;
            int rbase = tid >> 4;
#pragma unroll
            for (int i = 0; i < 4; ++i) {
                int row = rbase + i * 16;
                As[kk][row] = ldf(A, (long)(r0 + row) * lda + k0 + kk);
            }
        }
        if (!TRANS_B) {
            int cc = tid & 63;
            int kb = tid >> 6;
#pragma unroll
            for (int i = 0; i < 4; ++i) {
                int kk = kb + i * 4;
                Bs[kk][cc] = ldf(B, (long)(k0 + kk) * ldb + c0 + cc);
            }
        } else {
            int kk = tid & 15;
            int cb = tid >> 4;
#pragma unroll
            for (int i = 0; i < 4; ++i) {
                int cc = cb + i * 16;
                Bs[kk][cc] = ldf(B, (long)(c0 + cc) * ldb + k0 + kk);
            }
        }
        __syncthreads();
#pragma unroll
        for (int kk = 0; kk < 16; ++kk) {
            float4 a4 = *(const float4*)&As[kk][ty * 4];
            float4 b4 = *(const float4*)&Bs[kk][tx * 4];
            float av[4] = {a4.x, a4.y, a4.z, a4.w};
            float bv[4] = {b4.x, b4.y, b4.z, b4.w};
#pragma unroll
            for (int i = 0; i < 4; ++i)
#pragma unroll
                for (int j = 0; j < 4; ++j)
                    acc[i][j] = fmaf(av[i], bv[j], acc[i][j]);
        }
        __syncthreads();
    }

#pragma unroll
    for (int i = 0; i < 4; ++i) {
        int row = r0 + ty * 4 + i;
#pragma unroll
        for (int j = 0; j < 4; ++j) {
            int col = c0 + tx * 4 + j;
            float v = acc[i][j] * alpha;
            if (EPI == 1) v = __logf(fmaxf(v, 0.f) + EPSF);
            stf(C, (long)row * ldc + col, v);
        }
    }
}

// ---------------------------------------------------------------------------
// Row softmax over width 768 (unchanged, validated).
// ---------------------------------------------------------------------------
template <typename TO>
__global__ __launch_bounds__(256) void softmax_rows(const float* src, TO* dst)
{
    __shared__ float red[4];
    const long row = blockIdx.x;
    const float* s = src + row * Nc;
    TO* d = dst + row * Nc;
    const int tid = threadIdx.x;

    float v[3];
    float m = -1e30f;
#pragma unroll
    for (int i = 0; i < 3; ++i) { v[i] = s[tid + i * 256]; m = fmaxf(m, v[i]); }

#pragma unroll
    for (int off = 32; off > 0; off >>= 1) m = fmaxf(m, __shfl_down(m, off, 64));
    if ((tid & 63) == 0) red[tid >> 6] = m;
    __syncthreads();
    if (tid == 0) {
        float mm = red[0];
        for (int w = 1; w < 4; ++w) mm = fmaxf(mm, red[w]);
        red[0] = mm;
    }
    __syncthreads();
    m = red[0];
    __syncthreads();

    float e[3];
    float sum = 0.f;
#pragma unroll
    for (int i = 0; i < 3; ++i) { e[i] = __expf(v[i] - m); sum += e[i]; }
#pragma unroll
    for (int off = 32; off > 0; off >>= 1) sum += __shfl_down(sum, off, 64);
    if ((tid & 63) == 0) red[tid >> 6] = sum;
    __syncthreads();
    if (tid == 0) red[0] = red[0] + red[1] + red[2] + red[3];
    __syncthreads();
    const float inv = 1.f / fmaxf(red[0], 1e-30f);
#pragma unroll
    for (int i = 0; i < 3; ++i) stf(d, tid + i * 256, e[i] * inv);
}

// ---------------------------------------------------------------------------
// Gate network + Smix, 4 elements/thread. Tile: 16 n-rows x 64 m-cols.
// gelu(tanh) rewritten exactly as h*sigmoid(2z). Transposed reads via LDS
// (64x21 pad: reads are 2-way bank-aliased only = free).
// ---------------------------------------------------------------------------
__global__ __launch_bounds__(256) void gates_smix(
    const float* __restrict__ S1g, const float* __restrict__ S2g,
    const bf16* __restrict__ Crg, const bf16* __restrict__ Clg,
    float* __restrict__ Smixg, const float* __restrict__ smallf)
{
    __shared__ float t1t[64][21], t2t[64][21];
    __shared__ float cs[192];

    const long mat = (long)blockIdx.z * Nc * Nc;
    const float* S1 = S1g + mat;
    const float* S2 = S2g + mat;
    const unsigned short* Cr = (const unsigned short*)Crg + mat;
    const unsigned short* Cl = (const unsigned short*)Clg + mat;
    float* Smix = Smixg + mat;

    const int tid = threadIdx.x;
    if (tid < 192) cs[tid] = smallf[tid];

    const int m0 = blockIdx.x * 64, n0 = blockIdx.y * 16;
    {   // transposed tiles: S[m0..m0+63][n0..n0+15], coalesced float4 loads
        const int r = tid >> 2, c4 = (tid & 3) * 4;
        const float4 a = *(const float4*)&S1[(long)(m0 + r) * Nc + n0 + c4];
        const float4 b = *(const float4*)&S2[(long)(m0 + r) * Nc + n0 + c4];
        t1t[r][c4] = a.x; t1t[r][c4 + 1] = a.y; t1t[r][c4 + 2] = a.z; t1t[r][c4 + 3] = a.w;
        t2t[r][c4] = b.x; t2t[r][c4 + 1] = b.y; t2t[r][c4 + 2] = b.z; t2t[r][c4 + 3] = b.w;
    }
    __syncthreads();

    const float* cw1 = cs;       const float* cb1 = cs + 96;
    const float* cw2 = cs + 112; const float* cb2 = cs + 176;

    const int ty = tid >> 4, tx = tid & 15;
    const int n = n0 + ty;
    const long idx = (long)n * Nc + m0 + tx * 4;

    const float4 s1v = *(const float4*)&S1[idx];
    const float4 s2v = *(const float4*)&S2[idx];
    const uint2 cru = *(const uint2*)&Cr[idx];
    const uint2 clu = *(const uint2*)&Cl[idx];

    float s1a[4] = {s1v.x, s1v.y, s1v.z, s1v.w};
    float s2a[4] = {s2v.x, s2v.y, s2v.z, s2v.w};
    float cra[4] = {__uint_as_float((cru.x & 0xffffu) << 16),
                    __uint_as_float(cru.x & 0xffff0000u),
                    __uint_as_float((cru.y & 0xffffu) << 16),
                    __uint_as_float(cru.y & 0xffff0000u)};
    float cla[4] = {__uint_as_float((clu.x & 0xffffu) << 16),
                    __uint_as_float(clu.x & 0xffff0000u),
                    __uint_as_float((clu.y & 0xffffu) << 16),
                    __uint_as_float(clu.y & 0xffff0000u)};
    float s1t[4], s2t[4];
#pragma unroll
    for (int j = 0; j < 4; ++j) {
        s1t[j] = t1t[tx * 4 + j][ty];
        s2t[j] = t2t[tx * 4 + j][ty];
    }

    float g[4][4];
#pragma unroll
    for (int o = 0; o < 4; ++o)
#pragma unroll
        for (int j = 0; j < 4; ++j) g[o][j] = cb2[o];

#pragma unroll
    for (int u = 0; u < 16; ++u) {
        const float wf0 = cw1[u * 6 + 0], wf1 = cw1[u * 6 + 1], wf2 = cw1[u * 6 + 2];
        const float wf3 = cw1[u * 6 + 3], wf4 = cw1[u * 6 + 4], wf5 = cw1[u * 6 + 5];
        const float bu = cb1[u];
        float hid[4];
#pragma unroll
        for (int j = 0; j < 4; ++j) {
            float h = bu;
            h = fmaf(s1a[j], wf0, h);
            h = fmaf(s2a[j], wf1, h);
            h = fmaf(s1t[j], wf2, h);
            h = fmaf(s2t[j], wf3, h);
            h = fmaf(cra[j], wf4, h);
            h = fmaf(cla[j], wf5, h);
            // gelu_tanh(h) = h * sigmoid(2z), z = 0.79788456(h + 0.044715 h^3)
            const float hh = h * h;
            const float inner = fmaf(hh, 0.0356774081f, 0.7978845608f);
            const float z = h * inner;
            const float e = __expf(-2.f * z);       // e->inf => hid->0, no NaN
            hid[j] = h * __fdividef(1.f, 1.f + e);
        }
#pragma unroll
        for (int o = 0; o < 4; ++o) {
            const float w2o = cw2[o * 16 + u];
#pragma unroll
            for (int j = 0; j < 4; ++j) g[o][j] = fmaf(hid[j], w2o, g[o][j]);
        }
    }

    float out[4];
#pragma unroll
    for (int j = 0; j < 4; ++j) {
        const float ga = sigf(g[0][j]);
        const float go = sigf(g[1][j]);
        const float gn = sigf(g[2][j]);
        const float gc = sigf(g[3][j]);
        const float s1 = s1a[j], s2 = s2a[j];
        const float mx = fmaxf(s1, s2);
        const float lae = mx + __logf(1.f + __expf(-fabsf(s1 - s2)));
        out[j] = s1 + ga * s2 + go * (lae - s1) - gn * (BETA_NOT * s2) + gc * cra[j];
    }
    *(float4*)&Smix[idx] = (float4){out[0], out[1], out[2], out[3]};
}

// ---------------------------------------------------------------------------
__global__ __launch_bounds__(256) void combine_y(
    const float* __restrict__ y1, const float* __restrict__ y2,
    const float* __restrict__ smallf, float* __restrict__ y)
{
    const long i = (long)blockIdx.x * 256 + threadIdx.x;
    const int dk = (int)(i & 63);
    const long t = i >> 6;
    const int n = (int)(t % Nc);
    const long t2 = t / Nc;
    const int h = (int)(t2 & 7);
    const int b = (int)(t2 >> 3);
    const float w = 1.f / (1.f + __expf(-smallf[180]));
    const float v = y1[i] + w * y2[i];
    y[((long)(b * Nc + n)) * Dc + h * DKc + dk] = v;
}

__global__ __launch_bounds__(256) void store_out(
    const float* __restrict__ yo, const void* xraw, void* out)
{
    const int is32 = sniff_is_fp32(xraw);
    const long i = (long)blockIdx.x * 256 + threadIdx.x;
    if (i < (long)Bc * Nc * Dc) {
        if (is32) ((float*)out)[i] = yo[i];
        else      ((bf16*)out)[i] = __float2bfloat16(yo[i]);
    }
}

// ---------------------------------------------------------------------------
extern "C" void kernel_launch(void* const* d_in, const int* in_sizes, int n_in,
                              void* d_out, int out_size, void* d_ws, size_t ws_size,
                              hipStream_t stream)
{
    const size_t HD   = (size_t)BHc * Nc * DKc;   // 786432
    const size_t MAT  = (size_t)Nc * Nc;          // 589824
    const size_t MATS = (size_t)BHc * MAT;        // 9437184

    float* ws = (float*)d_ws;
    size_t off = 0;
    auto alloc = [&](size_t n) { float* p = ws + off; off += n; return p; };

    bf16* xb  = (bf16*)alloc(HD / 2);
    bf16* w1b = (bf16*)alloc(HD / 2);
    bf16* w2b = (bf16*)alloc(HD / 2);
    bf16* w1t = (bf16*)alloc(HD / 2);
    bf16* w2t = (bf16*)alloc(HD / 2);
    float* pwf    = alloc((size_t)Dc * Dc);
    float* smallf = alloc(192);
    float* q1 = alloc(HD); float* k1 = alloc(HD); float* v1 = alloc(HD);
    float* q2 = alloc(HD); float* k2 = alloc(HD); float* v2 = alloc(HD);
    float* S1   = alloc(MATS);
    float* S2   = alloc(MATS);
    float* Smix = alloc(MATS);
    bf16* A1b = (bf16*)alloc(MATS / 2);
    bf16* A2b = (bf16*)alloc(MATS / 2);
    bf16* Crb = (bf16*)alloc(MATS / 2);
    bf16* Clb = (bf16*)alloc(MATS / 2);
    float* tr  = alloc(HD);
    float* yb1 = alloc(HD);
    float* yb2 = alloc(HD);
    float* yc  = alloc(HD);
    float* yout = alloc(HD);

    // Transposes alias Smix (dead until gates; exactly 2*MATS bf16 = MATS fp32)
    bf16* A1tb = (bf16*)Smix;
    bf16* A2tb = ((bf16*)Smix) + MATS;

    const size_t NEED_BYTES = off * sizeof(float);
    if (ws_size < NEED_BYTES) {
        fill_sentinel<<<dim3(3072), 256, 0, stream>>>((unsigned short*)d_out);
        return;
    }

    // 0. normalize inputs
    convert_all<<<dim3(3072), 256, 0, stream>>>(
        d_in[0], d_in[1], d_in[2], d_in[3], d_in[4], d_in[5], d_in[6], d_in[7],
        d_in[8], xb, w1b, w2b, pwf, smallf);

    // 1. W transposes (512x1536 -> 1536x512), then QKV via MFMA (fp32 out)
    transpose_bf16<<<dim3(24, 8, 1), 256, 0, stream>>>(
        (const unsigned short*)w1b, (unsigned short*)w1t, Dc, 3 * Dc, 0, 0);
    transpose_bf16<<<dim3(24, 8, 1), 256, 0, stream>>>(
        (const unsigned short*)w2b, (unsigned short*)w2t, Dc, 3 * Dc, 0, 0);
    qkv_mfma<<<dim3(12, 12, 1), 256, 0, stream>>>(xb, w1t, q1, k1, v1);
    qkv_mfma<<<dim3(12, 12, 1), 256, 0, stream>>>(xb, w2t, q2, k2, v2);

    // 2. S = scale * q @ k^T per head (fp32, exact path)
    gemm_tile<float, float, float, true, 0><<<dim3(12, 12, BHc), 256, 0, stream>>>(
        q1, k1, S1, Nc, Nc, DKc, DKc, DKc, Nc, (long)Nc * DKc, (long)Nc * DKc, (long)MAT, SCALE);
    gemm_tile<float, float, float, true, 0><<<dim3(12, 12, BHc), 256, 0, stream>>>(
        q2, k2, S2, Nc, Nc, DKc, DKc, DKc, Nc, (long)Nc * DKc, (long)Nc * DKc, (long)MAT, SCALE);

    // 3. A1/A2 = softmax(S) -> bf16, then bf16 transposes (into Smix alias)
    softmax_rows<bf16><<<BHc * Nc, 256, 0, stream>>>(S1, A1b);
    softmax_rows<bf16><<<BHc * Nc, 256, 0, stream>>>(S2, A2b);
    transpose_bf16<<<dim3(12, 12, BHc), 256, 0, stream>>>(
        (const unsigned short*)A1b, (unsigned short*)A1tb, Nc, Nc, (long)MAT, (long)MAT);
    transpose_bf16<<<dim3(12, 12, BHc), 256, 0, stream>>>(
        (const unsigned short*)A2b, (unsigned short*)A2tb, Nc, Nc, (long)MAT, (long)MAT);

    // 4. Cr = log(A1@A2+eps), Cl = log(A2@A1+eps) via bf16 MFMA
    gemm_nt_mfma<1, bf16><<<dim3(6, 6, BHc), 256, 0, stream>>>(
        A1b, A2tb, Crb, Nc, Nc, Nc, (long)MAT, (long)MAT, (long)MAT, 1.f);
    gemm_nt_mfma<1, bf16><<<dim3(6, 6, BHc), 256, 0, stream>>>(
        A2b, A1tb, Clb, Nc, Nc, Nc, (long)MAT, (long)MAT, (long)MAT, 1.f);

    // 5. gates + Smix (vectorized 4/thread)
    gates_smix<<<dim3(12, 48, BHc), 256, 0, stream>>>(S1, S2, Crb, Clb, Smix, smallf);

    // 6. A = softmax(Smix) in place
    softmax_rows<float><<<BHc * Nc, 256, 0, stream>>>(Smix, Smix);

    // 7. transport = A2 @ v2
    gemm_tile<bf16, float, float, false, 0><<<dim3(1, 12, BHc), 256, 0, stream>>>(
        A2b, v2, tr, Nc, DKc, Nc, Nc, DKc, DKc, (long)MAT, (long)Nc * DKc, (long)Nc * DKc, 1.f);

    // 8. y_base = A @ v1 ; y_chain = A1 @ transport
    gemm_tile<float, float, float, false, 0><<<dim3(1, 12, BHc), 256, 0, stream>>>(
        Smix, v1, yb1, Nc, DKc, Nc, Nc, DKc, DKc, (long)MAT, (long)Nc * DKc, (long)Nc * DKc, 1.f);
    gemm_tile<bf16, float, float, false, 0><<<dim3(1, 12, BHc), 256, 0, stream>>>(
        A1b, tr, yb2, Nc, DKc, Nc, Nc, DKc, DKc, (long)MAT, (long)Nc * DKc, (long)Nc * DKc, 1.f);

    // 9. combine + layout
    combine_y<<<dim3(3072), 256, 0, stream>>>(yb1, yb2, smallf, yc);

    // 10. proj + dtype-aware store
    gemm_tile<float, float, float, false, 0><<<dim3(8, 24, 1), 256, 0, stream>>>(
        yc, pwf, yout, Bc * Nc, Dc, Dc, Dc, Dc, Dc, 0, 0, 0, 1.f);
    store_out<<<dim3(3072), 256, 0, stream>>>(yout, d_in[0], d_out);
}